// Round 11
// baseline (372.019 us; speedup 1.0000x reference)
//
#include <hip/hip_runtime.h>
#include <hip/hip_bf16.h>

typedef __attribute__((ext_vector_type(8))) short short8;
typedef __attribute__((ext_vector_type(4))) short short4v;
typedef __attribute__((ext_vector_type(4))) float f32x4;
typedef unsigned short u16;

#define T_ 4096
#define D_ 1024
#define ISSL2E (0.08838834764831845f * 1.4426950408889634f)   // 1/sqrt(128) * log2(e)

__device__ __forceinline__ u16 f2bf(float f) {
  union { float f; unsigned u; } v; v.f = f;
  unsigned r = v.u + 0x7FFFu + ((v.u >> 16) & 1u);
  return (u16)(r >> 16);
}

// ---------- fused 4-way pooling, fp32 -> bf16 ----------
__global__ __launch_bounds__(256) void pool_all(const float* __restrict__ x,
    u16* __restrict__ p1, u16* __restrict__ p2, u16* __restrict__ p4, u16* __restrict__ p8) {
  const int blk = blockIdx.x;
  const int b = blk >> 9, t0 = (blk & 511) << 3;
  const float* src = x + ((long)b * T_ + t0) * D_;
#pragma unroll
  for (int j = 0; j < 4; ++j) {
    const int c = threadIdx.x + j * 256;
    float v[8];
#pragma unroll
    for (int r = 0; r < 8; ++r) v[r] = src[r * D_ + c];
#pragma unroll
    for (int r = 0; r < 8; ++r) p1[((long)b * 4096 + t0 + r) * D_ + c] = f2bf(v[r]);
#pragma unroll
    for (int r = 0; r < 4; ++r)
      p2[((long)b * 2048 + (t0 >> 1) + r) * D_ + c] = f2bf((v[2*r] + v[2*r+1]) * 0.5f);
#pragma unroll
    for (int r = 0; r < 2; ++r)
      p4[((long)b * 1024 + (t0 >> 2) + r) * D_ + c] =
          f2bf((v[4*r] + v[4*r+1] + v[4*r+2] + v[4*r+3]) * 0.25f);
    p8[((long)b * 512 + (t0 >> 3)) * D_ + c] =
        f2bf((v[0]+v[1]+v[2]+v[3]+v[4]+v[5]+v[6]+v[7]) * 0.125f);
  }
}

// ---------- fused weight prep ----------
__global__ __launch_bounds__(256) void wprep(const float* __restrict__ Wq,
    const float* __restrict__ Wk, const float* __restrict__ Wv,
    const float* __restrict__ rW1, const float* __restrict__ Wout,
    u16* __restrict__ wqT, u16* __restrict__ kvT, u16* __restrict__ rw1T, u16* __restrict__ woutT) {
  const int idx = blockIdx.x * 256 + threadIdx.x;
  if (idx < 1048576) {
    const int h = idx >> 17, wi = idx & 131071;
    const int c = wi >> 10, k = wi & 1023;
    wqT[idx] = f2bf(Wq[(long)h * 131072 + k * 128 + c]);
  } else if (idx < 3145728) {
    const int lid = idx - 1048576;
    const int g = lid >> 19, wi = lid & 524287;
    const int n = wi >> 10, k = wi & 1023;
    const int kv = n >> 8, hh = (n >> 7) & 1, c = n & 127;
    const float* W = kv ? Wv : Wk;
    kvT[lid] = f2bf(W[(long)(2 * g + hh) * 131072 + k * 128 + c]);
  } else if (idx < 3407872) {
    const int lid = idx - 3145728;
    const int n = lid >> 10, k = lid & 1023;
    rw1T[lid] = f2bf(rW1[(long)k * 256 + n]);
  } else if (idx < 3538944) {
    const int lid = idx - 3407872;
    const int n = lid >> 7, k = lid & 127;
    woutT[lid] = f2bf(Wout[(long)k * 1024 + n]);
  }
}

// ---------- bf16 tiled transpose for K,V slices (V keys PV-permuted) ----------
__global__ __launch_bounds__(256) void tpose_all(const u16* __restrict__ KV,
                                                 u16* __restrict__ KT, u16* __restrict__ VT) {
  const int xt = blockIdx.x;
  int g, lx;
  if (xt < 128)      { g = 0; lx = xt; }
  else if (xt < 192) { g = 1; lx = xt - 128; }
  else if (xt < 224) { g = 2; lx = xt - 192; }
  else               { g = 3; lx = xt - 224; }
  const int Tk = 4096 >> g;
  const long kvrow[4] = {0, 8192, 12288, 14336};
  const long ktoff[4] = {0, 2097152, 3145728, 3670016};
  __shared__ u16 tile[32][33];
  const int z = blockIdx.z;
  const int b = z & 1, hh = (z >> 1) & 1, kv = z >> 2;
  const u16* src = KV + kvrow[g] * 512 + (long)b * Tk * 512 + kv * 256 + hh * 128;
  u16* dst = (kv ? VT : KT) + ktoff[g] + (long)(hh * 2 + b) * 128 * Tk;
  const int r0 = lx * 32, c0 = blockIdx.y * 32;
  const int ci = threadIdx.x & 31, ri = threadIdx.x >> 5;
#pragma unroll
  for (int j = 0; j < 4; ++j)
    tile[ri + 8 * j][ci] = src[(long)(r0 + ri + 8 * j) * 512 + c0 + ci];
  __syncthreads();
  const int key = r0 + ci;
  const int col = kv ? ((key & ~63) | (((key >> 4) & 1) << 5) | (((key >> 2) & 3) << 3)
                                    | (((key >> 5) & 1) << 2) | (key & 3))
                     : key;
#pragma unroll
  for (int j = 0; j < 4; ++j)
    dst[(long)(c0 + ri + 8 * j) * Tk + col] = tile[ci][ri + 8 * j];
}

// ---------- irfft of gains -> bf16 conv kernel, 4 phase replicas ----------
__global__ __launch_bounds__(256) void irfft_c(const float* __restrict__ bg, u16* __restrict__ crep) {
  const int h = blockIdx.y;
  const int Tk = 4096 >> (h >> 1);
  const int mask = Tk - 1;
  if ((int)(blockIdx.x * 256) >= Tk) return;
  const int nb = (Tk >> 1) + 1;
  __shared__ float ct[4096];
  __shared__ float wm[2049];
  const int tid = threadIdx.x;
  const float w0 = 6.283185307179586f / (float)Tk;
  for (int j = tid; j < Tk; j += 256) ct[j] = cosf(w0 * (float)j);
  for (int m = tid; m < nb; m += 256) {
    int band = (m * 8) / nb; if (band > 7) band = 7;
    const float g = 1.f / (1.f + expf(-bg[h * 8 + band]));
    const float sc = (m == 0 || m == nb - 1) ? 1.f : 2.f;
    wm[m] = g * sc / (float)Tk;
  }
  __syncthreads();
  const int n = blockIdx.x * 256 + tid;
  float acc = 0.f;
  int idx = 0;
  for (int m = 0; m < nb; ++m) {
    acc += wm[m] * ct[idx];
    idx += n;
    if (idx >= Tk) idx -= Tk;
  }
  const u16 bf = f2bf(acc);
  u16* hb = crep + (long)h * 16416;
#pragma unroll
  for (int p = 0; p < 4; ++p) {
    const int q = (n - p) & mask;
    hb[p * 4104 + q] = bf;
    if (q < 8) hb[p * 4104 + q + Tk] = bf;
  }
}

// ---------- async global->LDS ----------
__device__ __forceinline__ void gll16(const void* g, void* l) {
  __builtin_amdgcn_global_load_lds((const __attribute__((address_space(1))) void*)g,
                                   (__attribute__((address_space(3))) void*)l, 16, 0, 0);
}

// ---------- shared bf16 MFMA GEMM core (XOR-swizzled LDS) ----------
__device__ __forceinline__ void gemm_core(const u16* __restrict__ A, const u16* __restrict__ Bt,
    void* __restrict__ Cv, int K, int lda, int ldb, int ldc, int tm, int tn, float alpha,
    bool obf, u16 (*lds)[2][128][32]) {
  const int tid = threadIdx.x, lane = tid & 63, wid = tid >> 6;
  const int wr = wid >> 1, wc = wid & 1;
  const int srow = lane >> 2;
  const int scol = ((lane & 3) ^ ((lane >> 3) & 3)) * 8;
  const u16* ga0 = A + (long)(tm + 32 * wid + srow) * lda + scol;
  const u16* ga1 = ga0 + (long)16 * lda;
  const u16* gb0 = Bt + (long)(tn + 32 * wid + srow) * ldb + scol;
  const u16* gb1 = gb0 + (long)16 * ldb;
  f32x4 acc[4][4] = {};
  const int nk = K >> 5;
  gll16(ga0, &lds[0][0][32 * wid][0]);
  gll16(ga1, &lds[0][0][32 * wid + 16][0]);
  gll16(gb0, &lds[0][1][32 * wid][0]);
  gll16(gb1, &lds[0][1][32 * wid + 16][0]);
  int buf = 0;
  const int fr = lane & 15;
  const int fo2 = (((lane >> 4) & 3) ^ ((lane >> 1) & 3)) * 8;
  for (int kt = 0; kt < nk; ++kt) {
    __syncthreads();
    if (kt + 1 < nk) {
      const long ko = (long)(kt + 1) * 32;
      gll16(ga0 + ko, &lds[buf ^ 1][0][32 * wid][0]);
      gll16(ga1 + ko, &lds[buf ^ 1][0][32 * wid + 16][0]);
      gll16(gb0 + ko, &lds[buf ^ 1][1][32 * wid][0]);
      gll16(gb1 + ko, &lds[buf ^ 1][1][32 * wid + 16][0]);
    }
    short8 af[4], bfr[4];
#pragma unroll
    for (int i = 0; i < 4; ++i) {
      af[i]  = *(const short8*)&lds[buf][0][wr * 64 + i * 16 + fr][fo2];
      bfr[i] = *(const short8*)&lds[buf][1][wc * 64 + i * 16 + fr][fo2];
    }
#pragma unroll
    for (int i = 0; i < 4; ++i)
#pragma unroll
      for (int j = 0; j < 4; ++j)
        acc[i][j] = __builtin_amdgcn_mfma_f32_16x16x32_bf16(af[i], bfr[j], acc[i][j], 0, 0, 0);
    buf ^= 1;
  }
  const int er = (lane >> 4) * 4, ec = lane & 15;
  if (obf) {
    u16* C = (u16*)Cv;
#pragma unroll
    for (int i = 0; i < 4; ++i)
#pragma unroll
      for (int j = 0; j < 4; ++j)
#pragma unroll
        for (int r = 0; r < 4; ++r)
          C[(long)(tm + wr * 64 + i * 16 + er + r) * ldc + (tn + wc * 64 + j * 16 + ec)] =
              f2bf(acc[i][j][r] * alpha);
  } else {
    float* C = (float*)Cv;
#pragma unroll
    for (int i = 0; i < 4; ++i)
#pragma unroll
      for (int j = 0; j < 4; ++j)
#pragma unroll
        for (int r = 0; r < 4; ++r)
          C[(long)(tm + wr * 64 + i * 16 + er + r) * ldc + (tn + wc * 64 + j * 16 + ec)] =
              acc[i][j][r] * alpha;
  }
}

template <bool OBF>
__global__ __launch_bounds__(256) void gemm_bt(const u16* __restrict__ A, const u16* __restrict__ Bt,
                                               void* __restrict__ Cv, int K, int lda, int ldb, int ldc,
                                               long abs_, long bbs, long cbs, float alpha) {
  __shared__ u16 lds[2][2][128][32];
  const u16* Az = A + (long)blockIdx.z * abs_;
  const u16* Bz = Bt + (long)blockIdx.z * bbs;
  void* Cz = OBF ? (void*)((u16*)Cv + (long)blockIdx.z * cbs)
                 : (void*)((float*)Cv + (long)blockIdx.z * cbs);
  gemm_core(Az, Bz, Cz, K, lda, ldb, ldc, blockIdx.x * 128, blockIdx.y * 128, alpha, OBF, lds);
}

// ---------- mega-GEMM: Q + KV + router hidden ----------
__global__ __launch_bounds__(256) void gemm_p1(const u16* __restrict__ xbf,
    const u16* __restrict__ wqT, const u16* __restrict__ kvT, const u16* __restrict__ rw1T,
    u16* __restrict__ Qb, u16* __restrict__ KV, float* __restrict__ hid) {
  __shared__ u16 lds[2][2][128][32];
  const int id = blockIdx.x;
  if (id < 512) {
    gemm_core(xbf, wqT, Qb, 1024, 1024, 1024, 1024,
              (id >> 3) * 128, (id & 7) * 128, 1.f, true, lds);
  } else if (id < 992) {
    const int lid = id - 512;
    const int rt = lid >> 2, y = lid & 3;
    int g, lr;
    if (rt < 64)       { g = 0; lr = rt; }
    else if (rt < 96)  { g = 1; lr = rt - 64; }
    else if (rt < 112) { g = 2; lr = rt - 96; }
    else               { g = 3; lr = rt - 112; }
    const long xofs[4] = {0, 8388608, 12582912, 14680064};
    const long kvrow[4] = {0, 8192, 12288, 14336};
    gemm_core(xbf + xofs[g], kvT + (long)g * 524288, KV + kvrow[g] * 512,
              1024, 1024, 1024, 512, lr * 128, y * 128, 1.f, true, lds);
  } else {
    const int lid = id - 992;
    gemm_core(xbf, rw1T, hid, 1024, 1024, 1024, 256,
              (lid >> 1) * 128, (lid & 1) * 128, 1.f, false, lds);
  }
}

// ---------- circulant conv GEMM, BK=128 ----------
__global__ __launch_bounds__(256) void conv_k(const u16* __restrict__ crep,
    const u16* __restrict__ KT, u16* __restrict__ Kp) {
  const int z = blockIdx.z, h = z >> 1, b = z & 1, g = h >> 1;
  const int Tk = 4096 >> g, mask = Tk - 1;
  const int tm = blockIdx.x << 7;
  if (tm >= Tk) return;
  __shared__ u16 clds[16416];
  __shared__ u16 blds[2][4][128][32];
  const int tid = threadIdx.x, lane = tid & 63, wid = tid >> 6;
  const int wr = wid >> 1, wc = wid & 1;
  const int srow = lane >> 2;
  const int scol = ((lane & 3) ^ ((lane >> 3) & 3)) * 8;
  const int fr = lane & 15, fo = (lane >> 4) * 8;
  const int fo2 = (((lane >> 4) & 3) ^ ((lane >> 1) & 3)) * 8;
  {
    const short8* src = (const short8*)(crep + (long)h * 16416);
    short8* dst = (short8*)clds;
    for (int j = tid; j < 2052; j += 256) dst[j] = src[j];
  }
  const long ktofs = 4194304 - (4194304 >> g);
  const u16* Bt = KT + ktofs + (long)((h & 1) * 2 + b) * 128 * Tk;
  u16* out = Kp + ktofs + ((long)(h & 1) << 8) * Tk + ((long)b << 7) * Tk;
  const u16* gb0 = Bt + (long)(32 * wid + srow) * Tk + scol;
  const u16* gb1 = gb0 + (long)16 * Tk;
  f32x4 acc[4][4] = {};
  int base[4];
#pragma unroll
  for (int i = 0; i < 4; ++i) base[i] = (fo - (tm + wr * 64 + i * 16 + fr)) & mask;
  const int p = base[0] & 3;
  const u16* crow = clds + p * 4104;
  const int nk = Tk >> 7;
#pragma unroll
  for (int c = 0; c < 4; ++c) {
    gll16(gb0 + c * 32, &blds[0][c][32 * wid][0]);
    gll16(gb1 + c * 32, &blds[0][c][32 * wid + 16][0]);
  }
  int buf = 0;
  for (int kt = 0; kt < nk; ++kt) {
    __syncthreads();
    if (kt + 1 < nk) {
      const long ko = (long)(kt + 1) * 128;
#pragma unroll
      for (int c = 0; c < 4; ++c) {
        gll16(gb0 + ko + c * 32, &blds[buf ^ 1][c][32 * wid][0]);
        gll16(gb1 + ko + c * 32, &blds[buf ^ 1][c][32 * wid + 16][0]);
      }
    }
#pragma unroll
    for (int c = 0; c < 4; ++c) {
      short8 af[4], bfr[4];
#pragma unroll
      for (int i = 0; i < 4; ++i) {
        const int a0 = base[i] ^ p;
        short4v lo = *(const short4v*)(crow + a0);
        short4v hi = *(const short4v*)(crow + a0 + 4);
        af[i][0] = lo[0]; af[i][1] = lo[1]; af[i][2] = lo[2]; af[i][3] = lo[3];
        af[i][4] = hi[0]; af[i][5] = hi[1]; af[i][6] = hi[2]; af[i][7] = hi[3];
        base[i] = (base[i] + 32) & mask;
        bfr[i] = *(const short8*)&blds[buf][c][wc * 64 + i * 16 + fr][fo2];
      }
#pragma unroll
      for (int i = 0; i < 4; ++i)
#pragma unroll
        for (int j = 0; j < 4; ++j)
          acc[i][j] = __builtin_amdgcn_mfma_f32_16x16x32_bf16(af[i], bfr[j], acc[i][j], 0, 0, 0);
    }
    buf ^= 1;
  }
  const int er = (lane >> 4) * 4, ec = lane & 15;
#pragma unroll
  for (int i = 0; i < 4; ++i)
#pragma unroll
    for (int j = 0; j < 4; ++j)
#pragma unroll
      for (int r = 0; r < 4; ++r)
        out[(long)(tm + wr * 64 + i * 16 + er + r) * 128 + (wc * 64 + j * 16 + ec)] =
            f2bf(acc[i][j][r] * ISSL2E);
}

// ---------- flash v5: split-K jobs, single-V LDS (48KB -> 3 blocks/CU), partial O + (m,l) ----------
__global__ __launch_bounds__(256) void flash(const u16* __restrict__ Qb,
    const u16* __restrict__ Kp, const u16* __restrict__ VT,
    float* __restrict__ Op, float* __restrict__ mlb) {
  const int wg = blockIdx.x;
  const int x = wg & 7, s = wg >> 3;          // 1024 blocks: 8 XCD x 128 slots
  const int t5 = s >> 5;
  const int lvl = t5 ^ (t5 >> 1);             // gray: heavy groups pair with light
  const int hh = x >> 2, b = (x >> 1) & 1, kh = x & 1;
  const int h = lvl * 2 + hh;
  const int qtm = (s & 31) << 7;
  const int Tkf = 4096 >> lvl;                // full key range (strides)
  const int Tk2 = Tkf >> 1;                   // this job's keys
  const int nt = Tk2 >> 6;

  __shared__ __align__(16) char smem[49152];
  u16 (*Kl)[4][64][32] = (u16(*)[4][64][32])smem;          // 2 x 16 KB
  u16 (*Vl)[64]        = (u16(*)[64])(smem + 32768);       // 16 KB single buffer

  const int tid = threadIdx.x, lane = tid & 63, wid = tid >> 6;
  const int fr = lane & 15, gs = lane >> 4;
  const int fo = gs * 8;
  const int fo2 = ((gs & 3) ^ ((lane >> 1) & 3)) * 8;

  const long ktofs = 4194304 - (4194304 >> lvl);
  const u16* kbase = Kp + ktofs + (long)(hh * 2 + b) * 128 * Tkf + (long)kh * Tk2 * 128;
  const u16* vbase = VT + ktofs + (long)(hh * 2 + b) * 128 * Tkf;

  short8 aq[2][4];
#pragma unroll
  for (int m = 0; m < 2; ++m)
#pragma unroll
    for (int kk = 0; kk < 4; ++kk)
      aq[m][kk] = *(const short8*)(Qb +
          ((long)(b * 4096 + qtm + wid * 32 + m * 16 + fr)) * 1024 + h * 128 + kk * 32 + fo);

  const u16* kptr = kbase + (long)(lane >> 2) * 128 + wid * 32 +
                    (((lane & 3) ^ ((lane >> 3) & 3)) << 3);
  const u16* vptr = vbase + (long)(32 * wid + (lane >> 3)) * Tkf + kh * Tk2 +
                    (((lane & 7) ^ ((lane >> 3) & 7)) << 3);

  const char* kbL  = smem + fr * 64 + fo2 * 2;
  const char* vbL0 = smem + 32768 + fr * 128 + ((((gs    ) ^ (fr & 7)) & 7) << 4);
  const char* vbL1 = smem + 32768 + fr * 128 + ((((gs ^ 4) ^ (fr & 7)) & 7) << 4);

  f32x4 acc[2][8] = {};
  f32x4 accl[2] = {};
  float mr[2] = {-3e38f, -3e38f};

  short8 ones;
#pragma unroll
  for (int i = 0; i < 8; ++i) ones[i] = (short)0x3F80;

  // prologue: stage K(0)
#pragma unroll
  for (int i = 0; i < 4; ++i) gll16(kptr + i * 2048, &Kl[0][wid][i * 16][0]);

  int cur = 0;
  for (int kt = 0; kt < nt; ++kt) {
    asm volatile("s_waitcnt vmcnt(0)" ::: "memory");   // K(kt) ready; all Vl reads from PV(kt-1) done pre-barrier
    __builtin_amdgcn_sched_barrier(0);
    __builtin_amdgcn_s_barrier();
    __builtin_amdgcn_sched_barrier(0);
    // issue V(kt) FIRST (oldest -> covered by vmcnt(4)), then K(kt+1)
#pragma unroll
    for (int i = 0; i < 4; ++i)
      gll16(vptr + (long)kt * 64 + (long)i * 8 * Tkf, &Vl[32 * wid + 8 * i][0]);
    if (kt + 1 < nt) {
#pragma unroll
      for (int i = 0; i < 4; ++i)
        gll16(kptr + (long)(kt + 1) * 8192 + i * 2048, &Kl[cur ^ 1][wid][i * 16][0]);
    }
    const char* kc = kbL + cur * 16384;
    // ---- QK^T (swapped) ----
    f32x4 sa[2][4] = {};
    __builtin_amdgcn_s_setprio(1);
#pragma unroll
    for (int kk = 0; kk < 4; ++kk) {
      short8 bk[4];
#pragma unroll
      for (int jm = 0; jm < 4; ++jm)
        bk[jm] = *(const short8*)(kc + kk * 4096 + jm * 1024);
#pragma unroll
      for (int m = 0; m < 2; ++m)
#pragma unroll
        for (int jm = 0; jm < 4; ++jm)
          sa[m][jm] = __builtin_amdgcn_mfma_f32_16x16x32_bf16(bk[jm], aq[m][kk], sa[m][jm], 0, 0, 0);
    }
    __builtin_amdgcn_s_setprio(0);
    // ---- softmax (exp2 domain, defer-rescale) ----
    float tmx[2];
#pragma unroll
    for (int m = 0; m < 2; ++m) {
      float v0 = fmaxf(fmaxf(sa[m][0][0], sa[m][0][1]), fmaxf(sa[m][0][2], sa[m][0][3]));
      float v1 = fmaxf(fmaxf(sa[m][1][0], sa[m][1][1]), fmaxf(sa[m][1][2], sa[m][1][3]));
      float v2 = fmaxf(fmaxf(sa[m][2][0], sa[m][2][1]), fmaxf(sa[m][2][2], sa[m][2][3]));
      float v3 = fmaxf(fmaxf(sa[m][3][0], sa[m][3][1]), fmaxf(sa[m][3][2], sa[m][3][3]));
      float v = fmaxf(fmaxf(v0, v1), fmaxf(v2, v3));
      v = fmaxf(v, __shfl_xor(v, 16));
      v = fmaxf(v, __shfl_xor(v, 32));
      tmx[m] = v;
    }
    const bool need = (tmx[0] > mr[0] + 8.f) | (tmx[1] > mr[1] + 8.f);
    if (__any((int)need)) {
#pragma unroll
      for (int m = 0; m < 2; ++m) {
        const float mn = fmaxf(mr[m], tmx[m]);
        const float av = __builtin_amdgcn_exp2f(mr[m] - mn);
        mr[m] = mn;
#pragma unroll
        for (int jd = 0; jd < 8; ++jd)
#pragma unroll
          for (int r = 0; r < 4; ++r) acc[m][jd][r] *= av;
#pragma unroll
        for (int r = 0; r < 4; ++r) accl[m][r] *= av;
      }
    }
#pragma unroll
    for (int m = 0; m < 2; ++m)
#pragma unroll
      for (int jm = 0; jm < 4; ++jm)
#pragma unroll
        for (int r = 0; r < 4; ++r)
          sa[m][jm][r] = __builtin_amdgcn_exp2f(sa[m][jm][r] - mr[m]);
    // ---- pack P^T pairs in-register ----
    unsigned pk[2][4][2];
#pragma unroll
    for (int m = 0; m < 2; ++m)
#pragma unroll
      for (int jm = 0; jm < 4; ++jm) {
        asm("v_cvt_pk_bf16_f32 %0, %1, %2" : "=v"(pk[m][jm][0]) : "v"(sa[m][jm][0]), "v"(sa[m][jm][1]));
        asm("v_cvt_pk_bf16_f32 %0, %1, %2" : "=v"(pk[m][jm][1]) : "v"(sa[m][jm][2]), "v"(sa[m][jm][3]));
      }
    // ---- wait V(kt) (K(kt+1) stays in flight), barrier, PV ----
    if (kt + 1 < nt) { asm volatile("s_waitcnt vmcnt(4)" ::: "memory"); }
    else             { asm volatile("s_waitcnt vmcnt(0)" ::: "memory"); }
    __builtin_amdgcn_sched_barrier(0);
    __builtin_amdgcn_s_barrier();
    __builtin_amdgcn_sched_barrier(0);
    __builtin_amdgcn_s_setprio(1);
#pragma unroll
    for (int kk = 0; kk < 2; ++kk) {
      short8 pt[2];
#pragma unroll
      for (int m = 0; m < 2; ++m) {
        union { unsigned u[4]; short8 s; } pp;
        pp.u[0] = pk[m][kk][0];     pp.u[1] = pk[m][kk][1];
        pp.u[2] = pk[m][kk + 2][0]; pp.u[3] = pk[m][kk + 2][1];
        pt[m] = pp.s;
      }
      const char* vc = kk ? vbL1 : vbL0;
#pragma unroll
      for (int jd = 0; jd < 8; ++jd) {
        short8 bb = *(const short8*)(vc + jd * 2048);
#pragma unroll
        for (int m = 0; m < 2; ++m)
          acc[m][jd] = __builtin_amdgcn_mfma_f32_16x16x32_bf16(bb, pt[m], acc[m][jd], 0, 0, 0);
      }
#pragma unroll
      for (int m = 0; m < 2; ++m)
        accl[m] = __builtin_amdgcn_mfma_f32_16x16x32_bf16(ones, pt[m], accl[m], 0, 0, 0);
    }
    __builtin_amdgcn_s_setprio(0);
    cur ^= 1;
  }
  // ---- epilogue: write UNNORMALIZED partial O (transposed via LDS) + (m,l) ----
  __syncthreads();
  float* Ot = (float*)smem;             // [4 waves][16 q][132 d] = 33.8 KB
  float* ot = Ot + wid * 16 * 132;
  float* Obase = Op + (long)kh * 8388608;
#pragma unroll
  for (int m = 0; m < 2; ++m) {
#pragma unroll
    for (int jd = 0; jd < 8; ++jd) {
      f32x4 v;
#pragma unroll
      for (int r = 0; r < 4; ++r) v[r] = acc[m][jd][r];
      *(f32x4*)&ot[fr * 132 + jd * 16 + gs * 4] = v;
    }
    asm volatile("s_waitcnt lgkmcnt(0)" ::: "memory");
    __builtin_amdgcn_sched_barrier(0);
    const int q = qtm + wid * 32 + m * 16 + (lane >> 2);
    float* od = Obase + ((long)(b * 4096 + q) * 8 + h) * 128 + (lane & 3) * 32;
#pragma unroll
    for (int j = 0; j < 8; ++j) {
      f32x4 v = *(const f32x4*)&ot[(lane >> 2) * 132 + (lane & 3) * 32 + j * 4];
      *(f32x4*)&od[j * 4] = v;
    }
    asm volatile("s_waitcnt lgkmcnt(0)" ::: "memory");
    __builtin_amdgcn_sched_barrier(0);
    if (gs == 0) {
      const int q2 = qtm + wid * 32 + m * 16 + fr;
      ((float2*)mlb)[(long)kh * 65536 + (long)(b * 4096 + q2) * 8 + h] =
          make_float2(mr[m], accl[m][0]);
    }
  }
}

// ---------- combine the two key-half partials (in place into Op[0]) ----------
__global__ __launch_bounds__(256) void ocombine(float* __restrict__ Op, const float* __restrict__ mlb) {
  const int tok = blockIdx.x;           // b*4096 + t
  const int tid = threadIdx.x;
  __shared__ float e[8][2];
  if (tid < 8) {
    const float2 a = ((const float2*)mlb)[(long)tok * 8 + tid];
    const float2 c = ((const float2*)mlb)[65536 + (long)tok * 8 + tid];
    const float M = fmaxf(a.x, c.x);
    const float w1 = exp2f(a.x - M), w2 = exp2f(c.x - M);
    const float inv = 1.f / (w1 * a.y + w2 * c.y);
    e[tid][0] = w1 * inv;
    e[tid][1] = w2 * inv;
  }
  __syncthreads();
  const int h = tid >> 5, d4 = (tid & 31) << 2;
  float* p0 = Op + (long)tok * 1024 + h * 128 + d4;
  const float* p1 = p0 + 8388608;
  f32x4 o1 = *(f32x4*)p0;
  f32x4 o2 = *(const f32x4*)p1;
  const float e1 = e[h][0], e2 = e[h][1];
  f32x4 r;
#pragma unroll
  for (int i = 0; i < 4; ++i) r[i] = o1[i] * e1 + o2[i] * e2;
  *(f32x4*)p0 = r;
}

// ---------- fused router MLP tail + contra-flow + head mixing ----------
__global__ __launch_bounds__(256) void router_mix(const float* __restrict__ hid,
    const float* __restrict__ rb1, const float* __restrict__ rW2, const float* __restrict__ rb2,
    const float* __restrict__ al, const float* __restrict__ O, u16* __restrict__ mixed) {
  const int tok = blockIdx.x;
  const int b = tok >> 12, t = tok & 4095;
  const int tid = threadIdx.x;
  __shared__ float lred[4][8];
  __shared__ float wgt[8];
  __shared__ float ta[8];
  const float hv = fmaxf(hid[(long)tok * 256 + tid] + rb1[tid], 0.f);
  const float4* w4 = (const float4*)(rW2 + tid * 8);
  const float4 wa = w4[0], wb = w4[1];
  float part[8] = {hv * wa.x, hv * wa.y, hv * wa.z, hv * wa.w,
                   hv * wb.x, hv * wb.y, hv * wb.z, hv * wb.w};
#pragma unroll
  for (int h = 0; h < 8; ++h) {
    float v = part[h];
#pragma unroll
    for (int o = 1; o < 64; o <<= 1) v += __shfl_xor(v, o);
    if ((tid & 63) == 0) lred[tid >> 6][h] = v;
  }
  __syncthreads();
  if (tid < 8) ta[tid] = tanhf(al[tid]);
  if (tid == 0) {
    float lg[8], m = -1e30f;
#pragma unroll
    for (int h = 0; h < 8; ++h) {
      lg[h] = lred[0][h] + lred[1][h] + lred[2][h] + lred[3][h] + rb2[h];
      m = fmaxf(m, lg[h]);
    }
    float s = 0.f;
#pragma unroll
    for (int h = 0; h < 8; ++h) { lg[h] = __expf(lg[h] - m); s += lg[h]; }
    const float inv = 1.f / s;
#pragma unroll
    for (int h = 0; h < 8; ++h) wgt[h] = lg[h] * inv;
  }
  __syncthreads();
  if (tid < 128) {
    const long base = (long)tok * 1024 + tid;
    const long rbase = ((long)b * 4096 + (4095 - t)) * 1024 + tid;
    float acc = 0.f;
#pragma unroll
    for (int h = 0; h < 8; ++h)
      acc += wgt[h] * (O[base + h * 128] + ta[h] * O[rbase + h * 128]);
    mixed[(long)tok * 128 + tid] = f2bf(acc);
  }
}

extern "C" void kernel_launch(void* const* d_in, const int* in_sizes, int n_in,
                              void* d_out, int out_size, void* d_ws, size_t ws_size,
                              hipStream_t stream) {
  const float* x    = (const float*)d_in[0];
  const float* Wq   = (const float*)d_in[1];
  const float* Wk   = (const float*)d_in[2];
  const float* Wv   = (const float*)d_in[3];
  const float* bg   = (const float*)d_in[4];
  const float* al   = (const float*)d_in[5];
  const float* rW1  = (const float*)d_in[6];
  const float* rb1  = (const float*)d_in[7];
  const float* rW2  = (const float*)d_in[8];
  const float* rb2  = (const float*)d_in[9];
  const float* Wout = (const float*)d_in[10];
  float* out = (float*)d_out;

  // ---- arena (124 MB, lifetime overlays) ----
  const size_t MB = 1u << 20;
  char* w = (char*)d_ws;
  float* Opart = (float*)(w);              // 64 MB: [2][8192][8][128] fp32 [P4-P5]
  float* mlbuf = (float*)(w + 64 * MB);    //  1 MB: float2[2][8192][8]  [P4-P5]
  u16*   Kp    = (u16*)(w + 66 * MB);      // 7.5 MB [P3-P4]
  u16*   KT    = (u16*)(w + 74 * MB);      // 7.5 MB [P2-P3]
  u16*   VT    = (u16*)(w + 82 * MB);      // 7.5 MB [P2-P4]
  u16*   Qb    = (u16*)(w + 90 * MB);      // 16 MB [P1-P4]
  float* hid   = (float*)(w + 106 * MB);   //  8 MB [P1-P5]
  u16*   wqT   = (u16*)(w + 114 * MB);     //  2 MB
  u16*   kvT   = (u16*)(w + 116 * MB);     //  4 MB
  u16*   rw1T  = (u16*)(w + 120 * MB);     // 512 KB
  u16*   woutT = (u16*)(w + 120 * MB + 512 * 1024);  // 256 KB
  u16*   crep  = (u16*)(w + 121 * MB);     // 257 KB
  u16*   mixed = (u16*)(w + 122 * MB);     //  2 MB
  // overlays inside Opart's range (dead before P4):
  u16*   xbf   = (u16*)(w + 0);            // pools 0-30 MB [P0-P1]
  u16*   xp2   = (u16*)(w + 16 * MB);
  u16*   xp4   = (u16*)(w + 24 * MB);
  u16*   xp8   = (u16*)(w + 28 * MB);
  u16*   KV    = (u16*)(w + 30 * MB);      // 15 MB [P1-P2]

  // P0: pooling + weight prep
  pool_all<<<dim3(1024), dim3(256), 0, stream>>>(x, xbf, xp2, xp4, xp8);
  wprep<<<dim3(13824), dim3(256), 0, stream>>>(Wq, Wk, Wv, rW1, Wout, wqT, kvT, rw1T, woutT);

  // P1: all projections + router hidden
  gemm_p1<<<dim3(1120), dim3(256), 0, stream>>>(xbf, wqT, kvT, rw1T, Qb, KV, hid);

  // P2: K/V transposes + spectral kernel
  tpose_all<<<dim3(240, 4, 8), dim3(256), 0, stream>>>(KV, KT, VT);
  irfft_c<<<dim3(16, 8), dim3(256), 0, stream>>>(bg, crep);

  // P3: circulant conv
  conv_k<<<dim3(32, 1, 16), dim3(256), 0, stream>>>(crep, KT, Kp);

  // P4: flash v5 (split-K, 1024 jobs) + combine
  flash<<<dim3(1024), dim3(256), 0, stream>>>(Qb, Kp, VT, Opart, mlbuf);
  ocombine<<<dim3(8192), dim3(256), 0, stream>>>(Opart, mlbuf);

  // P5: router + mix, then output projection
  router_mix<<<dim3(8192), dim3(256), 0, stream>>>(hid, rb1, rW2, rb2, al, Opart, mixed);
  gemm_bt<false><<<dim3(64, 8), dim3(256), 0, stream>>>(mixed, woutT, out,
      128, 128, 128, 1024, 0, 0, 0, 1.f);
}

// Round 12
// 320.907 us; speedup vs baseline: 1.1593x; 1.1593x over previous
//
#include <hip/hip_runtime.h>
#include <hip/hip_bf16.h>

typedef __attribute__((ext_vector_type(8))) short short8;
typedef __attribute__((ext_vector_type(4))) short short4v;
typedef __attribute__((ext_vector_type(4))) float f32x4;
typedef unsigned short u16;

#define T_ 4096
#define D_ 1024
#define ISSL2E (0.08838834764831845f * 1.4426950408889634f)   // 1/sqrt(128) * log2(e)

__device__ __forceinline__ u16 f2bf(float f) {
  union { float f; unsigned u; } v; v.f = f;
  unsigned r = v.u + 0x7FFFu + ((v.u >> 16) & 1u);
  return (u16)(r >> 16);
}

// ---------- fused prep: 4-way pooling + all weight transposes in ONE launch ----------
__global__ __launch_bounds__(256) void prep_all(const float* __restrict__ x,
    const float* __restrict__ Wq, const float* __restrict__ Wk, const float* __restrict__ Wv,
    const float* __restrict__ rW1, const float* __restrict__ Wout,
    u16* __restrict__ p1, u16* __restrict__ p2, u16* __restrict__ p4, u16* __restrict__ p8,
    u16* __restrict__ wqT, u16* __restrict__ kvT, u16* __restrict__ rw1T, u16* __restrict__ woutT) {
  const int blk = blockIdx.x;
  if (blk < 1024) {
    const int b = blk >> 9, t0 = (blk & 511) << 3;
    const float* src = x + ((long)b * T_ + t0) * D_;
#pragma unroll
    for (int j = 0; j < 4; ++j) {
      const int c = threadIdx.x + j * 256;
      float v[8];
#pragma unroll
      for (int r = 0; r < 8; ++r) v[r] = src[r * D_ + c];
#pragma unroll
      for (int r = 0; r < 8; ++r) p1[((long)b * 4096 + t0 + r) * D_ + c] = f2bf(v[r]);
#pragma unroll
      for (int r = 0; r < 4; ++r)
        p2[((long)b * 2048 + (t0 >> 1) + r) * D_ + c] = f2bf((v[2*r] + v[2*r+1]) * 0.5f);
#pragma unroll
      for (int r = 0; r < 2; ++r)
        p4[((long)b * 1024 + (t0 >> 2) + r) * D_ + c] =
            f2bf((v[4*r] + v[4*r+1] + v[4*r+2] + v[4*r+3]) * 0.25f);
      p8[((long)b * 512 + (t0 >> 3)) * D_ + c] =
          f2bf((v[0]+v[1]+v[2]+v[3]+v[4]+v[5]+v[6]+v[7]) * 0.125f);
    }
    return;
  }
  const int idx = (blk - 1024) * 256 + threadIdx.x;
  if (idx < 1048576) {
    const int h = idx >> 17, wi = idx & 131071;
    const int c = wi >> 10, k = wi & 1023;
    wqT[idx] = f2bf(Wq[(long)h * 131072 + k * 128 + c]);
  } else if (idx < 3145728) {
    const int lid = idx - 1048576;
    const int g = lid >> 19, wi = lid & 524287;
    const int n = wi >> 10, k = wi & 1023;
    const int kv = n >> 8, hh = (n >> 7) & 1, c = n & 127;
    const float* W = kv ? Wv : Wk;
    kvT[lid] = f2bf(W[(long)(2 * g + hh) * 131072 + k * 128 + c]);
  } else if (idx < 3407872) {
    const int lid = idx - 3145728;
    const int n = lid >> 10, k = lid & 1023;
    rw1T[lid] = f2bf(rW1[(long)k * 256 + n]);
  } else if (idx < 3538944) {
    const int lid = idx - 3407872;
    const int n = lid >> 7, k = lid & 127;
    woutT[lid] = f2bf(Wout[(long)k * 1024 + n]);
  }
}

// ---------- bf16 tiled transpose for K,V slices (V keys PV-permuted) ----------
__global__ __launch_bounds__(256) void tpose_all(const u16* __restrict__ KV,
                                                 u16* __restrict__ KT, u16* __restrict__ VT) {
  const int xt = blockIdx.x;
  int g, lx;
  if (xt < 128)      { g = 0; lx = xt; }
  else if (xt < 192) { g = 1; lx = xt - 128; }
  else if (xt < 224) { g = 2; lx = xt - 192; }
  else               { g = 3; lx = xt - 224; }
  const int Tk = 4096 >> g;
  const long kvrow[4] = {0, 8192, 12288, 14336};
  const long ktoff[4] = {0, 2097152, 3145728, 3670016};
  __shared__ u16 tile[32][33];
  const int z = blockIdx.z;
  const int b = z & 1, hh = (z >> 1) & 1, kv = z >> 2;
  const u16* src = KV + kvrow[g] * 512 + (long)b * Tk * 512 + kv * 256 + hh * 128;
  u16* dst = (kv ? VT : KT) + ktoff[g] + (long)(hh * 2 + b) * 128 * Tk;
  const int r0 = lx * 32, c0 = blockIdx.y * 32;
  const int ci = threadIdx.x & 31, ri = threadIdx.x >> 5;
#pragma unroll
  for (int j = 0; j < 4; ++j)
    tile[ri + 8 * j][ci] = src[(long)(r0 + ri + 8 * j) * 512 + c0 + ci];
  __syncthreads();
  const int key = r0 + ci;
  const int col = kv ? ((key & ~63) | (((key >> 4) & 1) << 5) | (((key >> 2) & 3) << 3)
                                    | (((key >> 5) & 1) << 2) | (key & 3))
                     : key;
#pragma unroll
  for (int j = 0; j < 4; ++j)
    dst[(long)(c0 + ri + 8 * j) * Tk + col] = tile[ci][ri + 8 * j];
}

// ---------- irfft of gains -> bf16 conv kernel, 4 phase replicas ----------
__global__ __launch_bounds__(256) void irfft_c(const float* __restrict__ bg, u16* __restrict__ crep) {
  const int h = blockIdx.y;
  const int Tk = 4096 >> (h >> 1);
  const int mask = Tk - 1;
  if ((int)(blockIdx.x * 256) >= Tk) return;
  const int nb = (Tk >> 1) + 1;
  __shared__ float ct[4096];
  __shared__ float wm[2049];
  const int tid = threadIdx.x;
  const float w0 = 6.283185307179586f / (float)Tk;
  for (int j = tid; j < Tk; j += 256) ct[j] = cosf(w0 * (float)j);
  for (int m = tid; m < nb; m += 256) {
    int band = (m * 8) / nb; if (band > 7) band = 7;
    const float g = 1.f / (1.f + expf(-bg[h * 8 + band]));
    const float sc = (m == 0 || m == nb - 1) ? 1.f : 2.f;
    wm[m] = g * sc / (float)Tk;
  }
  __syncthreads();
  const int n = blockIdx.x * 256 + tid;
  float acc = 0.f;
  int idx = 0;
  for (int m = 0; m < nb; ++m) {
    acc += wm[m] * ct[idx];
    idx += n;
    if (idx >= Tk) idx -= Tk;
  }
  const u16 bf = f2bf(acc);
  u16* hb = crep + (long)h * 16416;
#pragma unroll
  for (int p = 0; p < 4; ++p) {
    const int q = (n - p) & mask;
    hb[p * 4104 + q] = bf;
    if (q < 8) hb[p * 4104 + q + Tk] = bf;
  }
}

// ---------- async global->LDS ----------
__device__ __forceinline__ void gll16(const void* g, void* l) {
  __builtin_amdgcn_global_load_lds((const __attribute__((address_space(1))) void*)g,
                                   (__attribute__((address_space(3))) void*)l, 16, 0, 0);
}

// ---------- shared bf16 MFMA GEMM core (XOR-swizzled LDS) ----------
__device__ __forceinline__ void gemm_core(const u16* __restrict__ A, const u16* __restrict__ Bt,
    void* __restrict__ Cv, int K, int lda, int ldb, int ldc, int tm, int tn, float alpha,
    bool obf, u16 (*lds)[2][128][32]) {
  const int tid = threadIdx.x, lane = tid & 63, wid = tid >> 6;
  const int wr = wid >> 1, wc = wid & 1;
  const int srow = lane >> 2;
  const int scol = ((lane & 3) ^ ((lane >> 3) & 3)) * 8;
  const u16* ga0 = A + (long)(tm + 32 * wid + srow) * lda + scol;
  const u16* ga1 = ga0 + (long)16 * lda;
  const u16* gb0 = Bt + (long)(tn + 32 * wid + srow) * ldb + scol;
  const u16* gb1 = gb0 + (long)16 * ldb;
  f32x4 acc[4][4] = {};
  const int nk = K >> 5;
  gll16(ga0, &lds[0][0][32 * wid][0]);
  gll16(ga1, &lds[0][0][32 * wid + 16][0]);
  gll16(gb0, &lds[0][1][32 * wid][0]);
  gll16(gb1, &lds[0][1][32 * wid + 16][0]);
  int buf = 0;
  const int fr = lane & 15;
  const int fo2 = (((lane >> 4) & 3) ^ ((lane >> 1) & 3)) * 8;
  for (int kt = 0; kt < nk; ++kt) {
    __syncthreads();
    if (kt + 1 < nk) {
      const long ko = (long)(kt + 1) * 32;
      gll16(ga0 + ko, &lds[buf ^ 1][0][32 * wid][0]);
      gll16(ga1 + ko, &lds[buf ^ 1][0][32 * wid + 16][0]);
      gll16(gb0 + ko, &lds[buf ^ 1][1][32 * wid][0]);
      gll16(gb1 + ko, &lds[buf ^ 1][1][32 * wid + 16][0]);
    }
    short8 af[4], bfr[4];
#pragma unroll
    for (int i = 0; i < 4; ++i) {
      af[i]  = *(const short8*)&lds[buf][0][wr * 64 + i * 16 + fr][fo2];
      bfr[i] = *(const short8*)&lds[buf][1][wc * 64 + i * 16 + fr][fo2];
    }
#pragma unroll
    for (int i = 0; i < 4; ++i)
#pragma unroll
      for (int j = 0; j < 4; ++j)
        acc[i][j] = __builtin_amdgcn_mfma_f32_16x16x32_bf16(af[i], bfr[j], acc[i][j], 0, 0, 0);
    buf ^= 1;
  }
  const int er = (lane >> 4) * 4, ec = lane & 15;
  if (obf) {
    u16* C = (u16*)Cv;
#pragma unroll
    for (int i = 0; i < 4; ++i)
#pragma unroll
      for (int j = 0; j < 4; ++j)
#pragma unroll
        for (int r = 0; r < 4; ++r)
          C[(long)(tm + wr * 64 + i * 16 + er + r) * ldc + (tn + wc * 64 + j * 16 + ec)] =
              f2bf(acc[i][j][r] * alpha);
  } else {
    float* C = (float*)Cv;
#pragma unroll
    for (int i = 0; i < 4; ++i)
#pragma unroll
      for (int j = 0; j < 4; ++j)
#pragma unroll
        for (int r = 0; r < 4; ++r)
          C[(long)(tm + wr * 64 + i * 16 + er + r) * ldc + (tn + wc * 64 + j * 16 + ec)] =
              acc[i][j][r] * alpha;
  }
}

template <bool OBF>
__global__ __launch_bounds__(256) void gemm_bt(const u16* __restrict__ A, const u16* __restrict__ Bt,
                                               void* __restrict__ Cv, int K, int lda, int ldb, int ldc,
                                               long abs_, long bbs, long cbs, float alpha) {
  __shared__ u16 lds[2][2][128][32];
  const u16* Az = A + (long)blockIdx.z * abs_;
  const u16* Bz = Bt + (long)blockIdx.z * bbs;
  void* Cz = OBF ? (void*)((u16*)Cv + (long)blockIdx.z * cbs)
                 : (void*)((float*)Cv + (long)blockIdx.z * cbs);
  gemm_core(Az, Bz, Cz, K, lda, ldb, ldc, blockIdx.x * 128, blockIdx.y * 128, alpha, OBF, lds);
}

// ---------- mega-GEMM: Q + KV + router hidden (XCD-swizzled job order) ----------
__global__ __launch_bounds__(256) void gemm_p1(const u16* __restrict__ xbf,
    const u16* __restrict__ wqT, const u16* __restrict__ kvT, const u16* __restrict__ rw1T,
    u16* __restrict__ Qb, u16* __restrict__ KV, float* __restrict__ hid) {
  __shared__ u16 lds[2][2][128][32];
  const int bid = blockIdx.x;
  const int id = (bid & 7) * 140 + (bid >> 3);   // bijective: 1120 = 8 XCDs x 140 jobs
  if (id < 512) {
    gemm_core(xbf, wqT, Qb, 1024, 1024, 1024, 1024,
              (id >> 3) * 128, (id & 7) * 128, 1.f, true, lds);
  } else if (id < 992) {
    const int lid = id - 512;
    const int rt = lid >> 2, y = lid & 3;
    int g, lr;
    if (rt < 64)       { g = 0; lr = rt; }
    else if (rt < 96)  { g = 1; lr = rt - 64; }
    else if (rt < 112) { g = 2; lr = rt - 96; }
    else               { g = 3; lr = rt - 112; }
    const long xofs[4] = {0, 8388608, 12582912, 14680064};
    const long kvrow[4] = {0, 8192, 12288, 14336};
    gemm_core(xbf + xofs[g], kvT + (long)g * 524288, KV + kvrow[g] * 512,
              1024, 1024, 1024, 512, lr * 128, y * 128, 1.f, true, lds);
  } else {
    const int lid = id - 992;
    gemm_core(xbf, rw1T, hid, 1024, 1024, 1024, 256,
              (lid >> 1) * 128, (lid & 1) * 128, 1.f, false, lds);
  }
}

// ---------- circulant conv GEMM, BK=128 ----------
__global__ __launch_bounds__(256) void conv_k(const u16* __restrict__ crep,
    const u16* __restrict__ KT, u16* __restrict__ Kp) {
  const int z = blockIdx.z, h = z >> 1, b = z & 1, g = h >> 1;
  const int Tk = 4096 >> g, mask = Tk - 1;
  const int tm = blockIdx.x << 7;
  if (tm >= Tk) return;
  __shared__ u16 clds[16416];
  __shared__ u16 blds[2][4][128][32];
  const int tid = threadIdx.x, lane = tid & 63, wid = tid >> 6;
  const int wr = wid >> 1, wc = wid & 1;
  const int srow = lane >> 2;
  const int scol = ((lane & 3) ^ ((lane >> 3) & 3)) * 8;
  const int fr = lane & 15, fo = (lane >> 4) * 8;
  const int fo2 = (((lane >> 4) & 3) ^ ((lane >> 1) & 3)) * 8;
  {
    const short8* src = (const short8*)(crep + (long)h * 16416);
    short8* dst = (short8*)clds;
    for (int j = tid; j < 2052; j += 256) dst[j] = src[j];
  }
  const long ktofs = 4194304 - (4194304 >> g);
  const u16* Bt = KT + ktofs + (long)((h & 1) * 2 + b) * 128 * Tk;
  u16* out = Kp + ktofs + ((long)(h & 1) << 8) * Tk + ((long)b << 7) * Tk;
  const u16* gb0 = Bt + (long)(32 * wid + srow) * Tk + scol;
  const u16* gb1 = gb0 + (long)16 * Tk;
  f32x4 acc[4][4] = {};
  int base[4];
#pragma unroll
  for (int i = 0; i < 4; ++i) base[i] = (fo - (tm + wr * 64 + i * 16 + fr)) & mask;
  const int p = base[0] & 3;
  const u16* crow = clds + p * 4104;
  const int nk = Tk >> 7;
#pragma unroll
  for (int c = 0; c < 4; ++c) {
    gll16(gb0 + c * 32, &blds[0][c][32 * wid][0]);
    gll16(gb1 + c * 32, &blds[0][c][32 * wid + 16][0]);
  }
  int buf = 0;
  for (int kt = 0; kt < nk; ++kt) {
    __syncthreads();
    if (kt + 1 < nk) {
      const long ko = (long)(kt + 1) * 128;
#pragma unroll
      for (int c = 0; c < 4; ++c) {
        gll16(gb0 + ko + c * 32, &blds[buf ^ 1][c][32 * wid][0]);
        gll16(gb1 + ko + c * 32, &blds[buf ^ 1][c][32 * wid + 16][0]);
      }
    }
#pragma unroll
    for (int c = 0; c < 4; ++c) {
      short8 af[4], bfr[4];
#pragma unroll
      for (int i = 0; i < 4; ++i) {
        const int a0 = base[i] ^ p;
        short4v lo = *(const short4v*)(crow + a0);
        short4v hi = *(const short4v*)(crow + a0 + 4);
        af[i][0] = lo[0]; af[i][1] = lo[1]; af[i][2] = lo[2]; af[i][3] = lo[3];
        af[i][4] = hi[0]; af[i][5] = hi[1]; af[i][6] = hi[2]; af[i][7] = hi[3];
        base[i] = (base[i] + 32) & mask;
        bfr[i] = *(const short8*)&blds[buf][c][wc * 64 + i * 16 + fr][fo2];
      }
#pragma unroll
      for (int i = 0; i < 4; ++i)
#pragma unroll
        for (int j = 0; j < 4; ++j)
          acc[i][j] = __builtin_amdgcn_mfma_f32_16x16x32_bf16(af[i], bfr[j], acc[i][j], 0, 0, 0);
    }
    buf ^= 1;
  }
  const int er = (lane >> 4) * 4, ec = lane & 15;
#pragma unroll
  for (int i = 0; i < 4; ++i)
#pragma unroll
    for (int j = 0; j < 4; ++j)
#pragma unroll
      for (int r = 0; r < 4; ++r)
        out[(long)(tm + wr * 64 + i * 16 + er + r) * 128 + (wc * 64 + j * 16 + ec)] =
            f2bf(acc[i][j][r] * ISSL2E);
}

// ---------- flash attention v4 (r10 known-good, reverted from split-K v5) ----------
__global__ __launch_bounds__(256, 2) void flash(const u16* __restrict__ Qb,
    const u16* __restrict__ Kp, const u16* __restrict__ VT, float* __restrict__ O) {
  const int wg = blockIdx.x;
  const int x = wg & 7, s = wg >> 3;
  const int t4 = s >> 4;
  const int lvl = t4 ^ (t4 >> 1);
  const int hh = x >> 2, b = (x >> 1) & 1;
  const int h = lvl * 2 + hh;
  const int qtm = (((x & 1) << 4) + (s & 15)) << 7;
  const int Tk = 4096 >> lvl;
  const int nt = Tk >> 6;

  __shared__ __align__(16) char smem[65536];
  u16 (*Kl)[4][64][32] = (u16(*)[4][64][32])smem;
  u16 (*Vl)[128][64]   = (u16(*)[128][64])(smem + 32768);

  const int tid = threadIdx.x, lane = tid & 63, wid = tid >> 6;
  const int fr = lane & 15, gs = lane >> 4;
  const int fo = gs * 8;
  const int fo2 = ((gs & 3) ^ ((lane >> 1) & 3)) * 8;

  const long ktofs = 4194304 - (4194304 >> lvl);
  const u16* kbase = Kp + ktofs + (long)(hh * 2 + b) * 128 * Tk;
  const u16* vbase = VT + ktofs + (long)(hh * 2 + b) * 128 * Tk;

  short8 aq[2][4];
#pragma unroll
  for (int m = 0; m < 2; ++m)
#pragma unroll
    for (int kk = 0; kk < 4; ++kk)
      aq[m][kk] = *(const short8*)(Qb +
          ((long)(b * 4096 + qtm + wid * 32 + m * 16 + fr)) * 1024 + h * 128 + kk * 32 + fo);

  const u16* kptr = kbase + (long)(lane >> 2) * 128 + wid * 32 +
                    (((lane & 3) ^ ((lane >> 3) & 3)) << 3);
  const u16* vptr = vbase + (long)(32 * wid + (lane >> 3)) * Tk +
                    (((lane & 7) ^ ((lane >> 3) & 7)) << 3);

  const char* kbL  = smem + fr * 64 + fo2 * 2;
  const char* vbL0 = smem + 32768 + fr * 128 + ((((gs    ) ^ (fr & 7)) & 7) << 4);
  const char* vbL1 = smem + 32768 + fr * 128 + ((((gs ^ 4) ^ (fr & 7)) & 7) << 4);

  f32x4 acc[2][8] = {};
  f32x4 accl[2] = {};
  float mr[2] = {-3e38f, -3e38f};

  short8 ones;
#pragma unroll
  for (int i = 0; i < 8; ++i) ones[i] = (short)0x3F80;

#pragma unroll
  for (int i = 0; i < 4; ++i) {
    gll16(kptr + i * 2048, &Kl[0][wid][i * 16][0]);
    gll16(vptr + (long)i * 8 * Tk, &Vl[0][32 * wid + 8 * i][0]);
  }

  int cur = 0;
  for (int kt = 0; kt < nt; ++kt) {
    asm volatile("s_waitcnt vmcnt(0)" ::: "memory");
    __builtin_amdgcn_sched_barrier(0);
    __builtin_amdgcn_s_barrier();
    __builtin_amdgcn_sched_barrier(0);
    if (kt + 1 < nt) {
      const int ktn = kt + 1;
#pragma unroll
      for (int i = 0; i < 4; ++i) {
        gll16(kptr + (long)ktn * 8192 + i * 2048, &Kl[cur ^ 1][wid][i * 16][0]);
        gll16(vptr + (long)ktn * 64 + (long)i * 8 * Tk, &Vl[cur ^ 1][32 * wid + 8 * i][0]);
      }
    }
    const char* kc = kbL + cur * 16384;
    f32x4 sa[2][4] = {};
    __builtin_amdgcn_s_setprio(1);
#pragma unroll
    for (int kk = 0; kk < 4; ++kk) {
      short8 bk[4];
#pragma unroll
      for (int jm = 0; jm < 4; ++jm)
        bk[jm] = *(const short8*)(kc + kk * 4096 + jm * 1024);
#pragma unroll
      for (int m = 0; m < 2; ++m)
#pragma unroll
        for (int jm = 0; jm < 4; ++jm)
          sa[m][jm] = __builtin_amdgcn_mfma_f32_16x16x32_bf16(bk[jm], aq[m][kk], sa[m][jm], 0, 0, 0);
    }
    __builtin_amdgcn_s_setprio(0);
    float tmx[2];
#pragma unroll
    for (int m = 0; m < 2; ++m) {
      float v0 = fmaxf(fmaxf(sa[m][0][0], sa[m][0][1]), fmaxf(sa[m][0][2], sa[m][0][3]));
      float v1 = fmaxf(fmaxf(sa[m][1][0], sa[m][1][1]), fmaxf(sa[m][1][2], sa[m][1][3]));
      float v2 = fmaxf(fmaxf(sa[m][2][0], sa[m][2][1]), fmaxf(sa[m][2][2], sa[m][2][3]));
      float v3 = fmaxf(fmaxf(sa[m][3][0], sa[m][3][1]), fmaxf(sa[m][3][2], sa[m][3][3]));
      float v = fmaxf(fmaxf(v0, v1), fmaxf(v2, v3));
      v = fmaxf(v, __shfl_xor(v, 16));
      v = fmaxf(v, __shfl_xor(v, 32));
      tmx[m] = v;
    }
    const bool need = (tmx[0] > mr[0] + 8.f) | (tmx[1] > mr[1] + 8.f);
    if (__any((int)need)) {
#pragma unroll
      for (int m = 0; m < 2; ++m) {
        const float mn = fmaxf(mr[m], tmx[m]);
        const float av = __builtin_amdgcn_exp2f(mr[m] - mn);
        mr[m] = mn;
#pragma unroll
        for (int jd = 0; jd < 8; ++jd)
#pragma unroll
          for (int r = 0; r < 4; ++r) acc[m][jd][r] *= av;
#pragma unroll
        for (int r = 0; r < 4; ++r) accl[m][r] *= av;
      }
    }
#pragma unroll
    for (int m = 0; m < 2; ++m)
#pragma unroll
      for (int jm = 0; jm < 4; ++jm)
#pragma unroll
        for (int r = 0; r < 4; ++r)
          sa[m][jm][r] = __builtin_amdgcn_exp2f(sa[m][jm][r] - mr[m]);
    unsigned pk[2][4][2];
#pragma unroll
    for (int m = 0; m < 2; ++m)
#pragma unroll
      for (int jm = 0; jm < 4; ++jm) {
        asm("v_cvt_pk_bf16_f32 %0, %1, %2" : "=v"(pk[m][jm][0]) : "v"(sa[m][jm][0]), "v"(sa[m][jm][1]));
        asm("v_cvt_pk_bf16_f32 %0, %1, %2" : "=v"(pk[m][jm][1]) : "v"(sa[m][jm][2]), "v"(sa[m][jm][3]));
      }
    const char* vc0 = vbL0 + cur * 16384;
    const char* vc1 = vbL1 + cur * 16384;
    __builtin_amdgcn_s_setprio(1);
#pragma unroll
    for (int kk = 0; kk < 2; ++kk) {
      short8 pt[2];
#pragma unroll
      for (int m = 0; m < 2; ++m) {
        union { unsigned u[4]; short8 s; } pp;
        pp.u[0] = pk[m][kk][0];     pp.u[1] = pk[m][kk][1];
        pp.u[2] = pk[m][kk + 2][0]; pp.u[3] = pk[m][kk + 2][1];
        pt[m] = pp.s;
      }
      const char* vc = kk ? vc1 : vc0;
#pragma unroll
      for (int jd = 0; jd < 8; ++jd) {
        short8 bb = *(const short8*)(vc + jd * 2048);
#pragma unroll
        for (int m = 0; m < 2; ++m)
          acc[m][jd] = __builtin_amdgcn_mfma_f32_16x16x32_bf16(bb, pt[m], acc[m][jd], 0, 0, 0);
      }
#pragma unroll
      for (int m = 0; m < 2; ++m)
        accl[m] = __builtin_amdgcn_mfma_f32_16x16x32_bf16(ones, pt[m], accl[m], 0, 0, 0);
    }
    __builtin_amdgcn_s_setprio(0);
    cur ^= 1;
  }
  __syncthreads();
  float* Ot = (float*)smem;
  float* ot = Ot + wid * 16 * 132;
#pragma unroll
  for (int m = 0; m < 2; ++m) {
    const float inv = 1.f / accl[m][0];
#pragma unroll
    for (int jd = 0; jd < 8; ++jd) {
      f32x4 v;
#pragma unroll
      for (int r = 0; r < 4; ++r) v[r] = acc[m][jd][r] * inv;
      *(f32x4*)&ot[fr * 132 + jd * 16 + gs * 4] = v;
    }
    asm volatile("s_waitcnt lgkmcnt(0)" ::: "memory");
    __builtin_amdgcn_sched_barrier(0);
    const int q = qtm + wid * 32 + m * 16 + (lane >> 2);
    float* od = O + ((long)(b * 4096 + q) * 8 + h) * 128 + (lane & 3) * 32;
#pragma unroll
    for (int j = 0; j < 8; ++j) {
      f32x4 v = *(const f32x4*)&ot[(lane >> 2) * 132 + (lane & 3) * 32 + j * 4];
      *(f32x4*)&od[j * 4] = v;
    }
    asm volatile("s_waitcnt lgkmcnt(0)" ::: "memory");
    __builtin_amdgcn_sched_barrier(0);
  }
}

// ---------- fused router MLP tail + contra-flow + head mixing ----------
__global__ __launch_bounds__(256) void router_mix(const float* __restrict__ hid,
    const float* __restrict__ rb1, const float* __restrict__ rW2, const float* __restrict__ rb2,
    const float* __restrict__ al, const float* __restrict__ O, u16* __restrict__ mixed) {
  const int tok = blockIdx.x;
  const int b = tok >> 12, t = tok & 4095;
  const int tid = threadIdx.x;
  __shared__ float lred[4][8];
  __shared__ float wgt[8];
  __shared__ float ta[8];
  const float hv = fmaxf(hid[(long)tok * 256 + tid] + rb1[tid], 0.f);
  const float4* w4 = (const float4*)(rW2 + tid * 8);
  const float4 wa = w4[0], wb = w4[1];
  float part[8] = {hv * wa.x, hv * wa.y, hv * wa.z, hv * wa.w,
                   hv * wb.x, hv * wb.y, hv * wb.z, hv * wb.w};
#pragma unroll
  for (int h = 0; h < 8; ++h) {
    float v = part[h];
#pragma unroll
    for (int o = 1; o < 64; o <<= 1) v += __shfl_xor(v, o);
    if ((tid & 63) == 0) lred[tid >> 6][h] = v;
  }
  __syncthreads();
  if (tid < 8) ta[tid] = tanhf(al[tid]);
  if (tid == 0) {
    float lg[8], m = -1e30f;
#pragma unroll
    for (int h = 0; h < 8; ++h) {
      lg[h] = lred[0][h] + lred[1][h] + lred[2][h] + lred[3][h] + rb2[h];
      m = fmaxf(m, lg[h]);
    }
    float s = 0.f;
#pragma unroll
    for (int h = 0; h < 8; ++h) { lg[h] = __expf(lg[h] - m); s += lg[h]; }
    const float inv = 1.f / s;
#pragma unroll
    for (int h = 0; h < 8; ++h) wgt[h] = lg[h] * inv;
  }
  __syncthreads();
  if (tid < 128) {
    const long base = (long)tok * 1024 + tid;
    const long rbase = ((long)b * 4096 + (4095 - t)) * 1024 + tid;
    float acc = 0.f;
#pragma unroll
    for (int h = 0; h < 8; ++h)
      acc += wgt[h] * (O[base + h * 128] + ta[h] * O[rbase + h * 128]);
    mixed[(long)tok * 128 + tid] = f2bf(acc);
  }
}

extern "C" void kernel_launch(void* const* d_in, const int* in_sizes, int n_in,
                              void* d_out, int out_size, void* d_ws, size_t ws_size,
                              hipStream_t stream) {
  const float* x    = (const float*)d_in[0];
  const float* Wq   = (const float*)d_in[1];
  const float* Wk   = (const float*)d_in[2];
  const float* Wv   = (const float*)d_in[3];
  const float* bg   = (const float*)d_in[4];
  const float* al   = (const float*)d_in[5];
  const float* rW1  = (const float*)d_in[6];
  const float* rb1  = (const float*)d_in[7];
  const float* rW2  = (const float*)d_in[8];
  const float* rb2  = (const float*)d_in[9];
  const float* Wout = (const float*)d_in[10];
  float* out = (float*)d_out;

  // ---- arena (lifetime overlays, ~95.5 MB) -- r10 layout ----
  const size_t MB = 1u << 20;
  char* w = (char*)d_ws;
  u16*   xbf   = (u16*)(w + 0);            // 16 MB [P0-P1]
  float* O     = (float*)(w + 0);          // 32 MB [P4-P5] overlays dead pools
  u16*   Qb    = (u16*)(w + 32 * MB);      // 16 MB [P1-P4]
  u16*   KV    = (u16*)(w + 48 * MB);      // 15 MB [P1-P2]
  u16*   Kp    = (u16*)(w + 48 * MB);      // 7.5MB [P3-P4] overlays dead KV
  u16*   KT    = (u16*)(w + 63 * MB);      // 7.5MB [P2-P3]
  u16*   VT    = (u16*)(w + 70 * MB + 512 * 1024); // 7.5MB [P2-P4]
  float* hid   = (float*)(w + 78 * MB);    //  8 MB [P1-P5]
  u16*   wqT   = (u16*)(w + 86 * MB);      //  2 MB
  u16*   kvT   = (u16*)(w + 88 * MB);      //  4 MB
  u16*   rw1T  = (u16*)(w + 92 * MB);      // 512 KB
  u16*   woutT = (u16*)(w + 92 * MB + 512 * 1024);   // 256 KB
  u16*   crep  = (u16*)(w + 92 * MB + 768 * 1024);   // 257 KB
  u16*   mixed = (u16*)(w + 93 * MB + 512 * 1024);   //  2 MB
  u16*   xp2   = (u16*)(w + 16 * MB);
  u16*   xp4   = (u16*)(w + 24 * MB);
  u16*   xp8   = (u16*)(w + 28 * MB);

  // P0: pooling + weight prep (one launch)
  prep_all<<<dim3(14848), dim3(256), 0, stream>>>(x, Wq, Wk, Wv, rW1, Wout,
      xbf, xp2, xp4, xp8, wqT, kvT, rw1T, woutT);

  // P1: all projections + router hidden (XCD-swizzled job order)
  gemm_p1<<<dim3(1120), dim3(256), 0, stream>>>(xbf, wqT, kvT, rw1T, Qb, KV, hid);

  // P2: K/V transposes + spectral kernel
  tpose_all<<<dim3(240, 4, 8), dim3(256), 0, stream>>>(KV, KT, VT);
  irfft_c<<<dim3(16, 8), dim3(256), 0, stream>>>(bg, crep);

  // P3: circulant conv (BK=128)
  conv_k<<<dim3(32, 1, 16), dim3(256), 0, stream>>>(crep, KT, Kp);

  // P4: flash v4
  flash<<<dim3(512), dim3(256), 0, stream>>>(Qb, Kp, VT, O);

  // P5: router + mix, then output projection
  router_mix<<<dim3(8192), dim3(256), 0, stream>>>(hid, rb1, rW2, rb2, al, O, mixed);
  gemm_bt<false><<<dim3(64, 8), dim3(256), 0, stream>>>(mixed, woutT, out,
      128, 128, 128, 1024, 0, 0, 0, 1.f);
}